// Round 8
// baseline (440.440 us; speedup 1.0000x reference)
//
#include <hip/hip_runtime.h>
#include <hip/hip_fp16.h>
#include <math.h>

#define NN 100000
#define EE 1600000
#define BB 64
#define CAP 48      // max in-degree; deg ~ Poisson(16), P(deg>=48) ~ 2e-10
#define ESPLIT 1048576                     // scatter half A size (with conv)

#define CONV_B ((NN + 15) / 16)            // 6250 conv blocks
#define SA_B (ESPLIT / 2048)               // 512 scatter-A blocks
#define CONVA_B (13 * ((CONV_B + 11) / 12))// 6773: conv grid, %13 routing
#define GEMM_B ((NN + 63) / 64)            // 1563 gemm blocks (64 nodes each)
#define SB_B (((EE - ESPLIT) + 2047) / 2048) // 270 scatter-B blocks
#define GEMMS_B (7 * SB_B)                 // 1890: gemm(L0) grid, %7 routing
#define NODE_B ((NN + 255) / 256)          // 391 blocks for node-wise passes

typedef _Float16 h2 __attribute__((ext_vector_type(2)));
typedef _Float16 f16x8 __attribute__((ext_vector_type(8)));
typedef float f32x4 __attribute__((ext_vector_type(4)));

__device__ __forceinline__ h2 h2bcast(float v) {
  _Float16 h = (_Float16)v; h2 r = { h, h }; return r;
}

__device__ __forceinline__ h2 lrelu_h2(h2 z) {
  const h2 c = { (_Float16)0.2f, (_Float16)0.2f };
  h2 zz = z * c;
#if __has_builtin(__builtin_elementwise_max)
  return __builtin_elementwise_max(z, zz);
#else
  h2 r; r.x = z.x > zz.x ? z.x : zz.x; r.y = z.y > zz.y ? z.y : zz.y; return r;
#endif
}

// ---- 8-edge scatter body (e0 multiple of 8, e0+8 <= EE guaranteed) ----
__device__ __forceinline__ void scatter8(int e0,
    const int* __restrict__ src, const int* __restrict__ dst,
    const float* __restrict__ ea, int* __restrict__ cursor,
    int2* __restrict__ pack)
{
  int4  d0 = *(const int4*)(dst + e0);
  int4  d1 = *(const int4*)(dst + e0 + 4);
  int4  s0 = *(const int4*)(src + e0);
  int4  s1 = *(const int4*)(src + e0 + 4);
  float4 a0 = *(const float4*)(ea + e0);
  float4 a1 = *(const float4*)(ea + e0 + 4);
  int p0 = atomicAdd(cursor + d0.x, 1);
  int p1 = atomicAdd(cursor + d0.y, 1);
  int p2 = atomicAdd(cursor + d0.z, 1);
  int p3 = atomicAdd(cursor + d0.w, 1);
  int p4 = atomicAdd(cursor + d1.x, 1);
  int p5 = atomicAdd(cursor + d1.y, 1);
  int p6 = atomicAdd(cursor + d1.z, 1);
  int p7 = atomicAdd(cursor + d1.w, 1);
  if (p0 < CAP) pack[(size_t)d0.x * CAP + p0] = make_int2(s0.x, __float_as_int(a0.x));
  if (p1 < CAP) pack[(size_t)d0.y * CAP + p1] = make_int2(s0.y, __float_as_int(a0.y));
  if (p2 < CAP) pack[(size_t)d0.z * CAP + p2] = make_int2(s0.z, __float_as_int(a0.z));
  if (p3 < CAP) pack[(size_t)d0.w * CAP + p3] = make_int2(s0.w, __float_as_int(a0.w));
  if (p4 < CAP) pack[(size_t)d1.x * CAP + p4] = make_int2(s1.x, __float_as_int(a1.x));
  if (p5 < CAP) pack[(size_t)d1.y * CAP + p5] = make_int2(s1.y, __float_as_int(a1.y));
  if (p6 < CAP) pack[(size_t)d1.z * CAP + p6] = make_int2(s1.z, __float_as_int(a1.z));
  if (p7 < CAP) pack[(size_t)d1.w * CAP + p7] = make_int2(s1.w, __float_as_int(a1.w));
}

// ---------- W pre-pack (TRANSPOSED, fp16 k-pairs) + zero cursor/gcnt/pooled ----------
__global__ __launch_bounds__(256) void wpack_kernel(
    const float* __restrict__ Wl0, const float* __restrict__ Wr0,
    const float* __restrict__ Wl1, const float* __restrict__ Wr1,
    unsigned int* __restrict__ Wp, int* __restrict__ cursor,
    int* __restrict__ gcnt, float* __restrict__ pooled)
{
  int t = blockIdx.x * 256 + threadIdx.x;
  if (t < NN) cursor[t] = 0;
  if (t < CAP + 1) gcnt[t] = 0;
  if (t < BB * 128) pooled[t] = 0.f;
  if (t < 32768) {
    int L = t >> 14;
    int rem = t & 16383;
    int ch = rem >> 6;
    int kk = rem & 63;
    const float* W = (L == 0) ? (ch < 128 ? Wl0 : Wr0) : (ch < 128 ? Wl1 : Wr1);
    int c = ch & 127;
    float v0 = W[(2 * kk) * 128 + c];
    float v1 = W[(2 * kk + 1) * 128 + c];
    h2 h = { (_Float16)v0, (_Float16)v1 };
    Wp[t] = __builtin_bit_cast(unsigned int, h);
  }
}

// ---------- counting sort by degree: hist -> prefix -> place ----------
__global__ __launch_bounds__(256) void hist_kernel(
    const int* __restrict__ cursor, int* __restrict__ gcnt)
{
  __shared__ int hh[CAP + 1];
  int tid = threadIdx.x;
  if (tid <= CAP) hh[tid] = 0;
  __syncthreads();
  int n = blockIdx.x * 256 + tid;
  if (n < NN) {
    int c = cursor[n]; if (c > CAP) c = CAP;
    atomicAdd(&hh[c], 1);
  }
  __syncthreads();
  if (tid <= CAP && hh[tid] > 0) atomicAdd(&gcnt[tid], hh[tid]);
}

__global__ __launch_bounds__(64) void prefix_kernel(
    const int* __restrict__ gcnt, int* __restrict__ gbase)
{
  if (threadIdx.x == 0) {
    int s = 0;
    for (int i = 0; i <= CAP; ++i) { gbase[i] = s; s += gcnt[i]; }
  }
}

__global__ __launch_bounds__(256) void place_kernel(
    const int* __restrict__ cursor, int* __restrict__ gbase,
    int* __restrict__ order)
{
  __shared__ int lh[CAP + 1];
  __shared__ int lb[CAP + 1];
  int tid = threadIdx.x;
  if (tid <= CAP) lh[tid] = 0;
  __syncthreads();
  int n = blockIdx.x * 256 + tid;
  int c = 0;
  if (n < NN) {
    c = cursor[n]; if (c > CAP) c = CAP;
    atomicAdd(&lh[c], 1);
  }
  __syncthreads();
  if (tid <= CAP) {
    int cnt = lh[tid];
    lb[tid] = cnt > 0 ? atomicAdd(&gbase[tid], cnt) : 0;
  }
  __syncthreads();
  if (tid <= CAP) lh[tid] = 0;
  __syncthreads();
  if (n < NN) {
    int s = atomicAdd(&lh[c], 1);
    order[lb[c] + s] = n;
  }
}

// ---------- fused: scatter half A (bid%13==0) + temporal conv (rest), interleaved ----------
__global__ __launch_bounds__(256) void conv_scatter_kernel(
    const float* __restrict__ x,
    const float* __restrict__ w1, const float* __restrict__ b1,
    const float* __restrict__ w2, const float* __restrict__ b2,
    __half* __restrict__ h16,
    const int* __restrict__ src, const int* __restrict__ dst,
    const float* __restrict__ ea,
    int* __restrict__ cursor, int2* __restrict__ pack)
{
  int tid = threadIdx.x;
  int r13 = blockIdx.x % 13;
  if (r13 == 0) {
    int sid = blockIdx.x / 13;
    int e0 = sid * 2048 + tid * 8;
    if (e0 >= ESPLIT) return;
    scatter8(e0, src, dst, ea, cursor, pack);
    return;
  }
  int cid = (blockIdx.x / 13) * 12 + (r13 - 1);
  if (cid >= CONV_B) return;
  __shared__ float s_x[16 * 36];
  __shared__ float s_c1[16 * 272];
  int n0 = cid * 16;

  for (int i = tid; i < 16 * 35; i += 256)
    s_x[(i / 35) * 36 + (i % 35)] = x[(size_t)n0 * 35 + i];

  int node = tid >> 4;
  int lane = tid & 15;

  float w1a = w1[lane * 3], w1b = w1[lane * 3 + 1], w1c = w1[lane * 3 + 2];
  float bb1 = b1[lane];
  float bb2 = b2[lane];

  __syncthreads();

  const float* row = s_x + node * 36;
  float xr[36];
#pragma unroll
  for (int i = 0; i < 9; ++i)
    *(float4*)&xr[4 * i] = *(const float4*)&row[4 * i];

  float* c1n = s_c1 + node * 272;
#pragma unroll
  for (int p = 0; p < 17; ++p) {
    float a = fmaf(w1a, xr[2 * p], fmaf(w1b, xr[2 * p + 1], fmaf(w1c, xr[2 * p + 2], bb1)));
    c1n[p * 16 + lane] = fmaxf(a, 0.f);
  }

  float w2r[48];
#pragma unroll
  for (int i = 0; i < 12; ++i)
    *(float4*)&w2r[4 * i] = *(const float4*)&w2[lane * 48 + 4 * i];

  __syncthreads();

  float acc8[8];
#pragma unroll
  for (int t = 0; t < 8; ++t) {
    float acc = bb2;
#pragma unroll
    for (int k = 0; k < 3; ++k) {
      const float4* rp = (const float4*)(c1n + (2 * t + k) * 16);
      float4 r0 = rp[0], r1 = rp[1], r2 = rp[2], r3 = rp[3];
      acc = fmaf(w2r[0  + k], r0.x, acc);
      acc = fmaf(w2r[3  + k], r0.y, acc);
      acc = fmaf(w2r[6  + k], r0.z, acc);
      acc = fmaf(w2r[9  + k], r0.w, acc);
      acc = fmaf(w2r[12 + k], r1.x, acc);
      acc = fmaf(w2r[15 + k], r1.y, acc);
      acc = fmaf(w2r[18 + k], r1.z, acc);
      acc = fmaf(w2r[21 + k], r1.w, acc);
      acc = fmaf(w2r[24 + k], r2.x, acc);
      acc = fmaf(w2r[27 + k], r2.y, acc);
      acc = fmaf(w2r[30 + k], r2.z, acc);
      acc = fmaf(w2r[33 + k], r2.w, acc);
      acc = fmaf(w2r[36 + k], r3.x, acc);
      acc = fmaf(w2r[39 + k], r3.y, acc);
      acc = fmaf(w2r[42 + k], r3.z, acc);
      acc = fmaf(w2r[45 + k], r3.w, acc);
    }
    acc8[t] = fmaxf(acc, 0.f);
  }

  h2 q0 = { (_Float16)acc8[0], (_Float16)acc8[1] };
  h2 q1 = { (_Float16)acc8[2], (_Float16)acc8[3] };
  h2 q2 = { (_Float16)acc8[4], (_Float16)acc8[5] };
  h2 q3 = { (_Float16)acc8[6], (_Float16)acc8[7] };
  int4 pk;
  pk.x = __builtin_bit_cast(int, q0);
  pk.y = __builtin_bit_cast(int, q1);
  pk.z = __builtin_bit_cast(int, q2);
  pk.w = __builtin_bit_cast(int, q3);
  *(int4*)(h16 + (size_t)(n0 + node) * 128 + lane * 8) = pk;
}

// ---------- dual GEMM on MFMA: per tile D = (W^T)·H ----------
__global__ __launch_bounds__(256) void gemm_dual(
    const __half* __restrict__ A16, const unsigned int* __restrict__ WpT,
    __half* __restrict__ Cl, __half* __restrict__ Cr,
    const int* __restrict__ src, const int* __restrict__ dst,
    const float* __restrict__ ea,
    int* __restrict__ cursor, int2* __restrict__ pack, int with_scatter)
{
  int tid = threadIdx.x;
  int gid = blockIdx.x;
  if (with_scatter) {
    int r7 = blockIdx.x % 7;
    if (r7 == 0) {
      int sid = blockIdx.x / 7;
      int e0 = ESPLIT + sid * 2048 + tid * 8;
      if (e0 >= EE) return;
      scatter8(e0, src, dst, ea, cursor, pack);
      return;
    }
    gid = (blockIdx.x / 7) * 6 + (r7 - 1);
    if (gid >= GEMM_B) return;
  }

  __shared__ uint4 sB[64 * 16];
  int row0 = gid * 64;
  for (int u = tid; u < 64 * 16; u += 256) {
    int node = u >> 4, cu = u & 15;
    uint4 v = { 0u, 0u, 0u, 0u };
    if (row0 + node < NN)
      v = *(const uint4*)(A16 + (size_t)(row0 + node) * 128 + cu * 8);
    sB[node * 16 + (cu ^ (node & 7))] = v;
  }
  __syncthreads();

  int wv = tid >> 6;
  int l  = tid & 63;
  int lr = l & 15;
  int lq = l >> 4;

  f32x4 acc[4][4];
#pragma unroll
  for (int ct = 0; ct < 4; ++ct)
#pragma unroll
    for (int nt = 0; nt < 4; ++nt)
      acc[ct][nt] = (f32x4){ 0.f, 0.f, 0.f, 0.f };

#pragma unroll
  for (int kc = 0; kc < 4; ++kc) {
    f16x8 afrag[4];
#pragma unroll
    for (int ct = 0; ct < 4; ++ct) {
      int ch = wv * 64 + ct * 16 + lr;
      int4 w = *(const int4*)(WpT + ch * 64 + kc * 16 + lq * 4);
      afrag[ct] = __builtin_bit_cast(f16x8, w);
    }
    f16x8 bfrag[4];
#pragma unroll
    for (int nt = 0; nt < 4; ++nt) {
      int node = nt * 16 + lr;
      int unit = kc * 4 + lq;
      uint4 v = sB[node * 16 + (unit ^ (node & 7))];
      bfrag[nt] = __builtin_bit_cast(f16x8, v);
    }
#pragma unroll
    for (int ct = 0; ct < 4; ++ct)
#pragma unroll
      for (int nt = 0; nt < 4; ++nt)
        acc[ct][nt] = __builtin_amdgcn_mfma_f32_16x16x32_f16(
            afrag[ct], bfrag[nt], acc[ct][nt], 0, 0, 0);
  }

  __half* Cb = (wv < 2) ? Cl : Cr;
#pragma unroll
  for (int ct = 0; ct < 4; ++ct) {
    int chm = ((wv & 1) * 64) + ct * 16 + lq * 4;
#pragma unroll
    for (int nt = 0; nt < 4; ++nt) {
      int node = row0 + nt * 16 + lr;
      if (node < NN) {
        h2 v0 = { (_Float16)acc[ct][nt][0], (_Float16)acc[ct][nt][1] };
        h2 v1 = { (_Float16)acc[ct][nt][2], (_Float16)acc[ct][nt][3] };
        uint2 u;
        u.x = __builtin_bit_cast(unsigned int, v0);
        u.y = __builtin_bit_cast(unsigned int, v1);
        *(uint2*)(Cb + (size_t)node * 128 + chm) = u;
      }
    }
  }
}

// ---------- fused GAT node kernel ----------
// 16 lanes/node; degree-sorted order (wave-uniform cnt); 8-edge blocks with a
// copy-free 2-stage A/B register pipeline (8 gathers in flight, 1 rescale / 8 edges).
__device__ __forceinline__ float edge_logit16(const h2 m0, const h2 m1, const h2 m2, const h2 m3,
                                              h2 wh, const h2* hrd, const h2* we, const h2* at)
{
  h2 z0 = m0 + (hrd[0] + wh * we[0]);
  h2 z1 = m1 + (hrd[1] + wh * we[1]);
  h2 z2 = m2 + (hrd[2] + wh * we[2]);
  h2 z3 = m3 + (hrd[3] + wh * we[3]);
  h2 d = lrelu_h2(z0) * at[0];
  d = lrelu_h2(z1) * at[1] + d;
  d = lrelu_h2(z2) * at[2] + d;
  d = lrelu_h2(z3) * at[3] + d;
  float pf = (float)d.x + (float)d.y;
  pf += __shfl_xor(pf, 1, 4);
  pf += __shfl_xor(pf, 2, 4);
  return pf;
}

#define LOADM(dst, idx) { int4 raw_ = *(const int4*)(hl + (size_t)(idx) * 128 + j8); \
  dst##0 = __builtin_bit_cast(h2, raw_.x); dst##1 = __builtin_bit_cast(h2, raw_.y);  \
  dst##2 = __builtin_bit_cast(h2, raw_.z); dst##3 = __builtin_bit_cast(h2, raw_.w); }

#define EL(Mp, w) edge_logit16(Mp##0, Mp##1, Mp##2, Mp##3, h2bcast(w), hrd, we, at)

#define LOAD8(P, base) { const int4* p4_ = (const int4*)(p + (base)); \
  P##c0 = p4_[0]; P##c1 = p4_[1]; P##c2 = p4_[2]; P##c3 = p4_[3]; \
  LOADM(P##m0, P##c0.x); LOADM(P##m1, P##c0.z); LOADM(P##m2, P##c1.x); LOADM(P##m3, P##c1.z); \
  LOADM(P##m4, P##c2.x); LOADM(P##m5, P##c2.z); LOADM(P##m6, P##c3.x); LOADM(P##m7, P##c3.z); }

#define PROC8(P) { \
  float w1 = __int_as_float(P##c0.y), w2 = __int_as_float(P##c0.w); \
  float w3 = __int_as_float(P##c1.y), w4 = __int_as_float(P##c1.w); \
  float w5 = __int_as_float(P##c2.y), w6 = __int_as_float(P##c2.w); \
  float w7 = __int_as_float(P##c3.y), w8 = __int_as_float(P##c3.w); \
  wsum += ((w1 + w2) + (w3 + w4)) + ((w5 + w6) + (w7 + w8)); \
  float q1 = EL(P##m0, w1), q2 = EL(P##m1, w2), q3 = EL(P##m2, w3), q4 = EL(P##m3, w4); \
  float q5 = EL(P##m4, w5), q6 = EL(P##m5, w6), q7 = EL(P##m6, w7), q8 = EL(P##m7, w8); \
  float mx = fmaxf(fmaxf(fmaxf(q1, q2), fmaxf(q3, q4)), fmaxf(fmaxf(q5, q6), fmaxf(q7, q8))); \
  float mn = fmaxf(m, mx); \
  float sc = exp2f(m - mn); \
  float t1 = exp2f(q1 - mn), t2 = exp2f(q2 - mn), t3 = exp2f(q3 - mn), t4 = exp2f(q4 - mn); \
  float t5 = exp2f(q5 - mn), t6 = exp2f(q6 - mn), t7 = exp2f(q7 - mn), t8 = exp2f(q8 - mn); \
  l = fmaf(l, sc, ((t1 + t2) + (t3 + t4)) + ((t5 + t6) + (t7 + t8))); \
  h2 sch = h2bcast(sc); \
  h2 T1 = h2bcast(t1), T2 = h2bcast(t2), T3 = h2bcast(t3), T4 = h2bcast(t4); \
  h2 T5 = h2bcast(t5), T6 = h2bcast(t6), T7 = h2bcast(t7), T8 = h2bcast(t8); \
  acc0 = acc0 * sch + (((T1 * P##m00 + T2 * P##m10) + (T3 * P##m20 + T4 * P##m30)) + \
                       ((T5 * P##m40 + T6 * P##m50) + (T7 * P##m60 + T8 * P##m70))); \
  acc1 = acc1 * sch + (((T1 * P##m01 + T2 * P##m11) + (T3 * P##m21 + T4 * P##m31)) + \
                       ((T5 * P##m41 + T6 * P##m51) + (T7 * P##m61 + T8 * P##m71))); \
  acc2 = acc2 * sch + (((T1 * P##m02 + T2 * P##m12) + (T3 * P##m22 + T4 * P##m32)) + \
                       ((T5 * P##m42 + T6 * P##m52) + (T7 * P##m62 + T8 * P##m72))); \
  acc3 = acc3 * sch + (((T1 * P##m03 + T2 * P##m13) + (T3 * P##m23 + T4 * P##m33)) + \
                       ((T5 * P##m43 + T6 * P##m53) + (T7 * P##m63 + T8 * P##m73))); \
  m = mn; }

__global__ __launch_bounds__(256) void gat_node_kernel(
    const int* __restrict__ order,
    const int* __restrict__ cnt_arr, const int2* __restrict__ pack,
    const __half* __restrict__ hl, const __half* __restrict__ hr,
    const float* __restrict__ We, const float* __restrict__ att,
    const float* __restrict__ bias, __half* __restrict__ out)
{
  int idx = blockIdx.x * 16 + (threadIdx.x >> 4);
  if (idx >= NN) return;
  int n = order[idx];
  int lq = threadIdx.x & 15;
  int j8 = lq * 8;

  const float RLN2 = 1.44269504088896340736f;
  int4 hraw = *(const int4*)(hr + (size_t)n * 128 + j8);
  h2 hrd[4] = { __builtin_bit_cast(h2, hraw.x), __builtin_bit_cast(h2, hraw.y),
                __builtin_bit_cast(h2, hraw.z), __builtin_bit_cast(h2, hraw.w) };
  float4 wf0 = *(const float4*)(We + j8);
  float4 wf1 = *(const float4*)(We + j8 + 4);
  h2 we[4] = { { (_Float16)wf0.x, (_Float16)wf0.y }, { (_Float16)wf0.z, (_Float16)wf0.w },
               { (_Float16)wf1.x, (_Float16)wf1.y }, { (_Float16)wf1.z, (_Float16)wf1.w } };
  float4 af0 = *(const float4*)(att + j8);
  float4 af1 = *(const float4*)(att + j8 + 4);
  h2 at[4] = { { (_Float16)(af0.x * RLN2), (_Float16)(af0.y * RLN2) },
               { (_Float16)(af0.z * RLN2), (_Float16)(af0.w * RLN2) },
               { (_Float16)(af1.x * RLN2), (_Float16)(af1.y * RLN2) },
               { (_Float16)(af1.z * RLN2), (_Float16)(af1.w * RLN2) } };

  int cnt = cnt_arr[n]; if (cnt > CAP) cnt = CAP;
  const int2* p = pack + (size_t)n * CAP;

  float m = -INFINITY, l = 0.f, wsum = 0.f;
  h2 zh = { (_Float16)0.f, (_Float16)0.f };
  h2 acc0 = zh, acc1 = zh, acc2 = zh, acc3 = zh;

  int4 Ac0, Ac1, Ac2, Ac3, Bc0, Bc1, Bc2, Bc3;
  h2 Am00, Am01, Am02, Am03, Am10, Am11, Am12, Am13;
  h2 Am20, Am21, Am22, Am23, Am30, Am31, Am32, Am33;
  h2 Am40, Am41, Am42, Am43, Am50, Am51, Am52, Am53;
  h2 Am60, Am61, Am62, Am63, Am70, Am71, Am72, Am73;
  h2 Bm00, Bm01, Bm02, Bm03, Bm10, Bm11, Bm12, Bm13;
  h2 Bm20, Bm21, Bm22, Bm23, Bm30, Bm31, Bm32, Bm33;
  h2 Bm40, Bm41, Bm42, Bm43, Bm50, Bm51, Bm52, Bm53;
  h2 Bm60, Bm61, Bm62, Bm63, Bm70, Bm71, Bm72, Bm73;

  int nb8 = cnt >> 3;
  if (nb8 > 0) {
    LOAD8(A, 0);
    int b = 0;
    for (;;) {
      if (b + 1 < nb8) { LOAD8(B, (b + 1) * 8); }
      PROC8(A);
      ++b; if (b >= nb8) break;
      if (b + 1 < nb8) { LOAD8(A, (b + 1) * 8); }
      PROC8(B);
      ++b; if (b >= nb8) break;
    }
  }
  for (int i = nb8 * 8; i < cnt; ++i) {
    int2 v1 = p[i];
    float w1 = __int_as_float(v1.y);
    h2 mm0, mm1, mm2, mm3;
    LOADM(mm, v1.x);
    wsum += w1;
    float p1 = EL(mm, w1);
    float mn = fmaxf(m, p1);
    float sc = exp2f(m - mn);
    float t1 = exp2f(p1 - mn);
    l = fmaf(l, sc, t1);
    h2 sch = h2bcast(sc), t1h = h2bcast(t1);
    acc0 = acc0 * sch + t1h * mm0;
    acc1 = acc1 * sch + t1h * mm1;
    acc2 = acc2 * sch + t1h * mm2;
    acc3 = acc3 * sch + t1h * mm3;
    m = mn;
  }

  // ---- self-loop: edge_attr = mean of incoming ea ----
  float la = wsum / fmaxf((float)cnt, 1.f);
  h2 sl0, sl1, sl2, sl3;
  LOADM(sl, n);
  float ps = EL(sl, la);
  float mn = fmaxf(m, ps);
  float sc = exp2f(m - mn);
  float ts = exp2f(ps - mn);
  l = fmaf(l, sc, ts);
  h2 sch = h2bcast(sc), tsh = h2bcast(ts);
  acc0 = acc0 * sch + tsh * sl0;
  acc1 = acc1 * sch + tsh * sl1;
  acc2 = acc2 * sch + tsh * sl2;
  acc3 = acc3 * sch + tsh * sl3;

  float inv = 1.f / l;
  float4 b0 = *(const float4*)(bias + j8);
  float4 b1 = *(const float4*)(bias + j8 + 4);
  h2 o0 = { (_Float16)fmaxf(fmaf((float)acc0.x, inv, b0.x), 0.f),
            (_Float16)fmaxf(fmaf((float)acc0.y, inv, b0.y), 0.f) };
  h2 o1 = { (_Float16)fmaxf(fmaf((float)acc1.x, inv, b0.z), 0.f),
            (_Float16)fmaxf(fmaf((float)acc1.y, inv, b0.w), 0.f) };
  h2 o2 = { (_Float16)fmaxf(fmaf((float)acc2.x, inv, b1.x), 0.f),
            (_Float16)fmaxf(fmaf((float)acc2.y, inv, b1.y), 0.f) };
  h2 o3 = { (_Float16)fmaxf(fmaf((float)acc3.x, inv, b1.z), 0.f),
            (_Float16)fmaxf(fmaf((float)acc3.y, inv, b1.w), 0.f) };
  int4 pk;
  pk.x = __builtin_bit_cast(int, o0);
  pk.y = __builtin_bit_cast(int, o1);
  pk.z = __builtin_bit_cast(int, o2);
  pk.w = __builtin_bit_cast(int, o3);
  *(int4*)(out + (size_t)n * 128 + j8) = pk;
}

// ---------- pool (batch is sorted, h fp16): 64 rows/block ----------
__global__ __launch_bounds__(128) void pool_kernel(
    const __half* __restrict__ h, const int* __restrict__ batch,
    float* __restrict__ pooled)
{
  int n0 = blockIdx.x * 64;
  if (n0 >= NN) return;
  int j = threadIdx.x;
  int nend = n0 + 64; if (nend > NN) nend = NN;
  float acc = 0.f;
  int curb = batch[n0];
  for (int n = n0; n < nend; ++n) {
    int b = batch[n];
    if (b != curb) {
      unsafeAtomicAdd(pooled + curb * 128 + j, acc);
      acc = 0.f; curb = b;
    }
    acc += __half2float(h[(size_t)n * 128 + j]);
  }
  unsafeAtomicAdd(pooled + curb * 128 + j, acc);
}

// ---------- fc ----------
__global__ __launch_bounds__(128) void fc_kernel(
    const float* __restrict__ pooled, const float* __restrict__ fcw,
    const float* __restrict__ fcb, float* __restrict__ out)
{
  int b = blockIdx.x;
  int t = threadIdx.x;
  float v = pooled[b * 128 + t] * fcw[t];
#pragma unroll
  for (int off = 32; off >= 1; off >>= 1) v += __shfl_down(v, off, 64);
  __shared__ float sbuf[2];
  if ((t & 63) == 0) sbuf[t >> 6] = v;
  __syncthreads();
  if (t == 0) out[b] = sbuf[0] + sbuf[1] + fcb[0];
}

extern "C" void kernel_launch(void* const* d_in, const int* in_sizes, int n_in,
                              void* d_out, int out_size, void* d_ws, size_t ws_size,
                              hipStream_t stream)
{
  const float* x    = (const float*)d_in[0];
  const int*   ei   = (const int*)d_in[1];
  const float* ea   = (const float*)d_in[2];
  const int*   batch= (const int*)d_in[3];
  const float* c1w  = (const float*)d_in[4];
  const float* c1b  = (const float*)d_in[5];
  const float* c2w  = (const float*)d_in[6];
  const float* c2b  = (const float*)d_in[7];
  const float* gWl[2] = { (const float*)d_in[8],  (const float*)d_in[13] };
  const float* gWr[2] = { (const float*)d_in[9],  (const float*)d_in[14] };
  const float* gWe[2] = { (const float*)d_in[10], (const float*)d_in[15] };
  const float* gAt[2] = { (const float*)d_in[11], (const float*)d_in[16] };
  const float* gB [2] = { (const float*)d_in[12], (const float*)d_in[17] };
  const float* fcw  = (const float*)d_in[18];
  const float* fcb  = (const float*)d_in[19];
  float* out = (float*)d_out;

  const int* src = ei;
  const int* dst = ei + EE;

  __half* h16    = (__half*)d_ws;                    // NN*128 fp16
  __half* hl     = h16 + (size_t)NN * 128;           // NN*128 fp16
  __half* hr     = hl + (size_t)NN * 128;            // NN*128 fp16
  int2*  pack    = (int2*)(hr + (size_t)NN * 128);   // NN*CAP int2
  int*   cursor  = (int*)(pack + (size_t)NN * CAP);  // NN i
  float* pooled  = (float*)(cursor + NN);            // BB*128 f
  unsigned int* Wp = (unsigned int*)(pooled + BB * 128); // 2 x 16384 u32 (WpT)
  int*   order   = (int*)(Wp + 32768);               // NN i
  int*   gcnt    = order + NN;                       // CAP+1 i
  int*   gbase   = gcnt + (CAP + 1);                 // CAP+1 i

  wpack_kernel<<<NODE_B, 256, 0, stream>>>(gWl[0], gWr[0], gWl[1], gWr[1],
                                           Wp, cursor, gcnt, pooled);

  conv_scatter_kernel<<<CONVA_B, 256, 0, stream>>>(
      x, c1w, c1b, c2w, c2b, h16, src, dst, ea, cursor, pack);

  // gemm L0 carries scatter half B; cursor complete when it finishes
  gemm_dual<<<GEMMS_B, 256, 0, stream>>>(
      h16, Wp, hl, hr, src, dst, ea, cursor, pack, 1);

  // degree counting sort (groups waves by cnt)
  hist_kernel<<<NODE_B, 256, 0, stream>>>(cursor, gcnt);
  prefix_kernel<<<1, 64, 0, stream>>>(gcnt, gbase);
  place_kernel<<<NODE_B, 256, 0, stream>>>(cursor, gbase, order);

  gat_node_kernel<<<(NN + 15) / 16, 256, 0, stream>>>(order, cursor, pack, hl, hr,
                                                      gWe[0], gAt[0], gB[0], h16);

  gemm_dual<<<GEMM_B, 256, 0, stream>>>(
      h16, Wp + 16384, hl, hr, src, dst, ea, cursor, pack, 0);
  gat_node_kernel<<<(NN + 15) / 16, 256, 0, stream>>>(order, cursor, pack, hl, hr,
                                                      gWe[1], gAt[1], gB[1], h16);

  pool_kernel<<<(NN + 63) / 64, 128, 0, stream>>>(h16, batch, pooled);
  fc_kernel<<<BB, 128, 0, stream>>>(pooled, fcw, fcb, out);
}

// Round 9
// 401.784 us; speedup vs baseline: 1.0962x; 1.0962x over previous
//
#include <hip/hip_runtime.h>
#include <hip/hip_fp16.h>
#include <math.h>

#define NN 100000
#define EE 1600000
#define BB 64
#define CAP 48      // max in-degree; deg ~ Poisson(16), P(deg>=48) ~ 2e-10
#define EHALF 800000

#define CONV_B ((NN + 15) / 16)            // 6250 conv blocks
#define SBH ((EHALF + 2047) / 2048)        // 391 scatter blocks per half (8 edges/thread)
#define CONVA_B (CONV_B + SBH)             // 6641: conv kernel grid (%17 routing)
#define GEMM_B ((NN + 63) / 64)            // 1563 gemm blocks (64 nodes each)
#define GEMMS_B (GEMM_B + SBH)             // 1954: gemm(L0) grid (%5 routing)
#define NODE_B ((NN + 255) / 256)          // 391 blocks for node-wise passes

typedef _Float16 h2 __attribute__((ext_vector_type(2)));
typedef _Float16 f16x8 __attribute__((ext_vector_type(8)));
typedef float f32x4 __attribute__((ext_vector_type(4)));

__device__ __forceinline__ h2 h2bcast(float v) {
  _Float16 h = (_Float16)v; h2 r = { h, h }; return r;
}

__device__ __forceinline__ h2 lrelu_h2(h2 z) {
  const h2 c = { (_Float16)0.2f, (_Float16)0.2f };
  h2 zz = z * c;
#if __has_builtin(__builtin_elementwise_max)
  return __builtin_elementwise_max(z, zz);
#else
  h2 r; r.x = z.x > zz.x ? z.x : zz.x; r.y = z.y > zz.y ? z.y : zz.y; return r;
#endif
}

// ---- 8-edge scatter body (e0 multiple of 8, e0+8 <= EE guaranteed) ----
__device__ __forceinline__ void scatter8(int e0,
    const int* __restrict__ src, const int* __restrict__ dst,
    const float* __restrict__ ea, int* __restrict__ cursor,
    int2* __restrict__ pack)
{
  int4  d0 = *(const int4*)(dst + e0);
  int4  d1 = *(const int4*)(dst + e0 + 4);
  int4  s0 = *(const int4*)(src + e0);
  int4  s1 = *(const int4*)(src + e0 + 4);
  float4 a0 = *(const float4*)(ea + e0);
  float4 a1 = *(const float4*)(ea + e0 + 4);
  int p0 = atomicAdd(cursor + d0.x, 1);
  int p1 = atomicAdd(cursor + d0.y, 1);
  int p2 = atomicAdd(cursor + d0.z, 1);
  int p3 = atomicAdd(cursor + d0.w, 1);
  int p4 = atomicAdd(cursor + d1.x, 1);
  int p5 = atomicAdd(cursor + d1.y, 1);
  int p6 = atomicAdd(cursor + d1.z, 1);
  int p7 = atomicAdd(cursor + d1.w, 1);
  if (p0 < CAP) pack[(size_t)d0.x * CAP + p0] = make_int2(s0.x, __float_as_int(a0.x));
  if (p1 < CAP) pack[(size_t)d0.y * CAP + p1] = make_int2(s0.y, __float_as_int(a0.y));
  if (p2 < CAP) pack[(size_t)d0.z * CAP + p2] = make_int2(s0.z, __float_as_int(a0.z));
  if (p3 < CAP) pack[(size_t)d0.w * CAP + p3] = make_int2(s0.w, __float_as_int(a0.w));
  if (p4 < CAP) pack[(size_t)d1.x * CAP + p4] = make_int2(s1.x, __float_as_int(a1.x));
  if (p5 < CAP) pack[(size_t)d1.y * CAP + p5] = make_int2(s1.y, __float_as_int(a1.y));
  if (p6 < CAP) pack[(size_t)d1.z * CAP + p6] = make_int2(s1.z, __float_as_int(a1.z));
  if (p7 < CAP) pack[(size_t)d1.w * CAP + p7] = make_int2(s1.w, __float_as_int(a1.w));
}

// ---------- W pre-pack (TRANSPOSED, fp16 k-pairs) + zero cursor/gcnt/relbase/pooled ----------
__global__ __launch_bounds__(256) void wpack_kernel(
    const float* __restrict__ Wl0, const float* __restrict__ Wr0,
    const float* __restrict__ Wl1, const float* __restrict__ Wr1,
    unsigned int* __restrict__ Wp, int* __restrict__ cursor,
    int* __restrict__ gcnt, int* __restrict__ relbase,
    float* __restrict__ pooled)
{
  int t = blockIdx.x * 256 + threadIdx.x;
  if (t < NN) cursor[t] = 0;
  if (t < CAP + 1) { gcnt[t] = 0; relbase[t] = 0; }
  if (t < BB * 128) pooled[t] = 0.f;
  if (t < 32768) {
    int L = t >> 14;
    int rem = t & 16383;
    int ch = rem >> 6;
    int kk = rem & 63;
    const float* W = (L == 0) ? (ch < 128 ? Wl0 : Wr0) : (ch < 128 ? Wl1 : Wr1);
    int c = ch & 127;
    float v0 = W[(2 * kk) * 128 + c];
    float v1 = W[(2 * kk + 1) * 128 + c];
    h2 h = { (_Float16)v0, (_Float16)v1 };
    Wp[t] = __builtin_bit_cast(unsigned int, h);
  }
}

// ---------- counting sort by degree: hist -> place (local prefix, fused) ----------
__global__ __launch_bounds__(256) void hist_kernel(
    const int* __restrict__ cursor, int* __restrict__ gcnt)
{
  __shared__ int hh[CAP + 1];
  int tid = threadIdx.x;
  if (tid <= CAP) hh[tid] = 0;
  __syncthreads();
  int n = blockIdx.x * 256 + tid;
  if (n < NN) {
    int c = cursor[n]; if (c > CAP) c = CAP;
    atomicAdd(&hh[c], 1);
  }
  __syncthreads();
  if (tid <= CAP && hh[tid] > 0) atomicAdd(&gcnt[tid], hh[tid]);
}

__global__ __launch_bounds__(256) void place_kernel(
    const int* __restrict__ cursor, const int* __restrict__ gcnt,
    int* __restrict__ relbase, int* __restrict__ order)
{
  __shared__ int lh[CAP + 1];
  __shared__ int lb[CAP + 1];
  __shared__ int pfx[CAP + 1];
  int tid = threadIdx.x;
  if (tid <= CAP) lh[tid] = 0;
  if (tid == 0) {           // local exclusive prefix of the (complete) global hist
    int s = 0;
    for (int i = 0; i <= CAP; ++i) { pfx[i] = s; s += gcnt[i]; }
  }
  __syncthreads();
  int n = blockIdx.x * 256 + tid;
  int c = 0;
  if (n < NN) {
    c = cursor[n]; if (c > CAP) c = CAP;
    atomicAdd(&lh[c], 1);
  }
  __syncthreads();
  if (tid <= CAP) {
    int cnt = lh[tid];
    lb[tid] = cnt > 0 ? (pfx[tid] + atomicAdd(&relbase[tid], cnt)) : 0;
  }
  __syncthreads();
  if (tid <= CAP) lh[tid] = 0;
  __syncthreads();
  if (n < NN) {
    int s = atomicAdd(&lh[c], 1);
    order[lb[c] + s] = n;
  }
}

// ---------- fused: scatter half A (bid%17==0) + temporal conv (rest), interleaved ----------
__global__ __launch_bounds__(256) void conv_scatter_kernel(
    const float* __restrict__ x,
    const float* __restrict__ w1, const float* __restrict__ b1,
    const float* __restrict__ w2, const float* __restrict__ b2,
    __half* __restrict__ h16,
    const int* __restrict__ src, const int* __restrict__ dst,
    const float* __restrict__ ea,
    int* __restrict__ cursor, int2* __restrict__ pack)
{
  int tid = threadIdx.x;
  int r17 = blockIdx.x % 17;
  if (r17 == 0) {
    int sid = blockIdx.x / 17;
    int e0 = sid * 2048 + tid * 8;
    if (e0 >= EHALF) return;
    scatter8(e0, src, dst, ea, cursor, pack);
    return;
  }
  int cid = (blockIdx.x / 17) * 16 + (r17 - 1);
  if (cid >= CONV_B) return;
  __shared__ float s_x[16 * 36];
  __shared__ float s_c1[16 * 272];
  int n0 = cid * 16;

  for (int i = tid; i < 16 * 35; i += 256)
    s_x[(i / 35) * 36 + (i % 35)] = x[(size_t)n0 * 35 + i];

  int node = tid >> 4;
  int lane = tid & 15;

  float w1a = w1[lane * 3], w1b = w1[lane * 3 + 1], w1c = w1[lane * 3 + 2];
  float bb1 = b1[lane];
  float bb2 = b2[lane];

  __syncthreads();

  const float* row = s_x + node * 36;
  float xr[36];
#pragma unroll
  for (int i = 0; i < 9; ++i)
    *(float4*)&xr[4 * i] = *(const float4*)&row[4 * i];

  float* c1n = s_c1 + node * 272;
#pragma unroll
  for (int p = 0; p < 17; ++p) {
    float a = fmaf(w1a, xr[2 * p], fmaf(w1b, xr[2 * p + 1], fmaf(w1c, xr[2 * p + 2], bb1)));
    c1n[p * 16 + lane] = fmaxf(a, 0.f);
  }

  float w2r[48];
#pragma unroll
  for (int i = 0; i < 12; ++i)
    *(float4*)&w2r[4 * i] = *(const float4*)&w2[lane * 48 + 4 * i];

  __syncthreads();

  float acc8[8];
#pragma unroll
  for (int t = 0; t < 8; ++t) {
    float acc = bb2;
#pragma unroll
    for (int k = 0; k < 3; ++k) {
      const float4* rp = (const float4*)(c1n + (2 * t + k) * 16);
      float4 r0 = rp[0], r1 = rp[1], r2 = rp[2], r3 = rp[3];
      acc = fmaf(w2r[0  + k], r0.x, acc);
      acc = fmaf(w2r[3  + k], r0.y, acc);
      acc = fmaf(w2r[6  + k], r0.z, acc);
      acc = fmaf(w2r[9  + k], r0.w, acc);
      acc = fmaf(w2r[12 + k], r1.x, acc);
      acc = fmaf(w2r[15 + k], r1.y, acc);
      acc = fmaf(w2r[18 + k], r1.z, acc);
      acc = fmaf(w2r[21 + k], r1.w, acc);
      acc = fmaf(w2r[24 + k], r2.x, acc);
      acc = fmaf(w2r[27 + k], r2.y, acc);
      acc = fmaf(w2r[30 + k], r2.z, acc);
      acc = fmaf(w2r[33 + k], r2.w, acc);
      acc = fmaf(w2r[36 + k], r3.x, acc);
      acc = fmaf(w2r[39 + k], r3.y, acc);
      acc = fmaf(w2r[42 + k], r3.z, acc);
      acc = fmaf(w2r[45 + k], r3.w, acc);
    }
    acc8[t] = fmaxf(acc, 0.f);
  }

  h2 q0 = { (_Float16)acc8[0], (_Float16)acc8[1] };
  h2 q1 = { (_Float16)acc8[2], (_Float16)acc8[3] };
  h2 q2 = { (_Float16)acc8[4], (_Float16)acc8[5] };
  h2 q3 = { (_Float16)acc8[6], (_Float16)acc8[7] };
  int4 pk;
  pk.x = __builtin_bit_cast(int, q0);
  pk.y = __builtin_bit_cast(int, q1);
  pk.z = __builtin_bit_cast(int, q2);
  pk.w = __builtin_bit_cast(int, q3);
  *(int4*)(h16 + (size_t)(n0 + node) * 128 + lane * 8) = pk;
}

// ---------- dual GEMM on MFMA: per tile D = (W^T)·H ----------
__global__ __launch_bounds__(256) void gemm_dual(
    const __half* __restrict__ A16, const unsigned int* __restrict__ WpT,
    __half* __restrict__ Cl, __half* __restrict__ Cr,
    const int* __restrict__ src, const int* __restrict__ dst,
    const float* __restrict__ ea,
    int* __restrict__ cursor, int2* __restrict__ pack, int with_scatter)
{
  int tid = threadIdx.x;
  int gid = blockIdx.x;
  if (with_scatter) {
    int r5 = blockIdx.x % 5;
    if (r5 == 0) {
      int sid = blockIdx.x / 5;
      int e0 = EHALF + sid * 2048 + tid * 8;
      if (e0 >= EE) return;
      scatter8(e0, src, dst, ea, cursor, pack);
      return;
    }
    gid = (blockIdx.x / 5) * 4 + (r5 - 1);
    if (gid >= GEMM_B) return;
  }

  __shared__ uint4 sB[64 * 16];
  int row0 = gid * 64;
  for (int u = tid; u < 64 * 16; u += 256) {
    int node = u >> 4, cu = u & 15;
    uint4 v = { 0u, 0u, 0u, 0u };
    if (row0 + node < NN)
      v = *(const uint4*)(A16 + (size_t)(row0 + node) * 128 + cu * 8);
    sB[node * 16 + (cu ^ (node & 7))] = v;
  }
  __syncthreads();

  int wv = tid >> 6;
  int l  = tid & 63;
  int lr = l & 15;
  int lq = l >> 4;

  f32x4 acc[4][4];
#pragma unroll
  for (int ct = 0; ct < 4; ++ct)
#pragma unroll
    for (int nt = 0; nt < 4; ++nt)
      acc[ct][nt] = (f32x4){ 0.f, 0.f, 0.f, 0.f };

#pragma unroll
  for (int kc = 0; kc < 4; ++kc) {
    f16x8 afrag[4];
#pragma unroll
    for (int ct = 0; ct < 4; ++ct) {
      int ch = wv * 64 + ct * 16 + lr;
      int4 w = *(const int4*)(WpT + ch * 64 + kc * 16 + lq * 4);
      afrag[ct] = __builtin_bit_cast(f16x8, w);
    }
    f16x8 bfrag[4];
#pragma unroll
    for (int nt = 0; nt < 4; ++nt) {
      int node = nt * 16 + lr;
      int unit = kc * 4 + lq;
      uint4 v = sB[node * 16 + (unit ^ (node & 7))];
      bfrag[nt] = __builtin_bit_cast(f16x8, v);
    }
#pragma unroll
    for (int ct = 0; ct < 4; ++ct)
#pragma unroll
      for (int nt = 0; nt < 4; ++nt)
        acc[ct][nt] = __builtin_amdgcn_mfma_f32_16x16x32_f16(
            afrag[ct], bfrag[nt], acc[ct][nt], 0, 0, 0);
  }

  __half* Cb = (wv < 2) ? Cl : Cr;
#pragma unroll
  for (int ct = 0; ct < 4; ++ct) {
    int chm = ((wv & 1) * 64) + ct * 16 + lq * 4;
#pragma unroll
    for (int nt = 0; nt < 4; ++nt) {
      int node = row0 + nt * 16 + lr;
      if (node < NN) {
        h2 v0 = { (_Float16)acc[ct][nt][0], (_Float16)acc[ct][nt][1] };
        h2 v1 = { (_Float16)acc[ct][nt][2], (_Float16)acc[ct][nt][3] };
        uint2 u;
        u.x = __builtin_bit_cast(unsigned int, v0);
        u.y = __builtin_bit_cast(unsigned int, v1);
        *(uint2*)(Cb + (size_t)node * 128 + chm) = u;
      }
    }
  }
}

// ---------- fused GAT node kernel: packed-fp16, degree-sorted HEAVY-FIRST order ----------
// 16 lanes/node; 4-edge blocks, 1-ahead prefetch (proven R7 shape).
__device__ __forceinline__ float edge_logit16(const h2 m0, const h2 m1, const h2 m2, const h2 m3,
                                              h2 wh, const h2* hrd, const h2* we, const h2* at)
{
  h2 z0 = m0 + (hrd[0] + wh * we[0]);
  h2 z1 = m1 + (hrd[1] + wh * we[1]);
  h2 z2 = m2 + (hrd[2] + wh * we[2]);
  h2 z3 = m3 + (hrd[3] + wh * we[3]);
  h2 d = lrelu_h2(z0) * at[0];
  d = lrelu_h2(z1) * at[1] + d;
  d = lrelu_h2(z2) * at[2] + d;
  d = lrelu_h2(z3) * at[3] + d;
  float pf = (float)d.x + (float)d.y;
  pf += __shfl_xor(pf, 1, 4);
  pf += __shfl_xor(pf, 2, 4);
  return pf;
}

#define LOADM(dst, idx) { int4 raw_ = *(const int4*)(hl + (size_t)(idx) * 128 + j8); \
  dst##0 = __builtin_bit_cast(h2, raw_.x); dst##1 = __builtin_bit_cast(h2, raw_.y);  \
  dst##2 = __builtin_bit_cast(h2, raw_.z); dst##3 = __builtin_bit_cast(h2, raw_.w); }

__global__ __launch_bounds__(256) void gat_node_kernel(
    const int* __restrict__ order,
    const int* __restrict__ cnt_arr, const int2* __restrict__ pack,
    const __half* __restrict__ hl, const __half* __restrict__ hr,
    const float* __restrict__ We, const float* __restrict__ att,
    const float* __restrict__ bias, __half* __restrict__ out)
{
  int idx = blockIdx.x * 16 + (threadIdx.x >> 4);
  if (idx >= NN) return;
  int n = order[(NN - 1) - idx];   // heavy-first: LPT scheduling, tiny blocks drain the tail
  int lq = threadIdx.x & 15;
  int j8 = lq * 8;

  const float RLN2 = 1.44269504088896340736f;
  int4 hraw = *(const int4*)(hr + (size_t)n * 128 + j8);
  h2 hrd[4] = { __builtin_bit_cast(h2, hraw.x), __builtin_bit_cast(h2, hraw.y),
                __builtin_bit_cast(h2, hraw.z), __builtin_bit_cast(h2, hraw.w) };
  float4 wf0 = *(const float4*)(We + j8);
  float4 wf1 = *(const float4*)(We + j8 + 4);
  h2 we[4] = { { (_Float16)wf0.x, (_Float16)wf0.y }, { (_Float16)wf0.z, (_Float16)wf0.w },
               { (_Float16)wf1.x, (_Float16)wf1.y }, { (_Float16)wf1.z, (_Float16)wf1.w } };
  float4 af0 = *(const float4*)(att + j8);
  float4 af1 = *(const float4*)(att + j8 + 4);
  h2 at[4] = { { (_Float16)(af0.x * RLN2), (_Float16)(af0.y * RLN2) },
               { (_Float16)(af0.z * RLN2), (_Float16)(af0.w * RLN2) },
               { (_Float16)(af1.x * RLN2), (_Float16)(af1.y * RLN2) },
               { (_Float16)(af1.z * RLN2), (_Float16)(af1.w * RLN2) } };

  int cnt = cnt_arr[n]; if (cnt > CAP) cnt = CAP;
  const int2* p = pack + (size_t)n * CAP;

  float m = -INFINITY, l = 0.f, wsum = 0.f;
  h2 zh = { (_Float16)0.f, (_Float16)0.f };
  h2 acc0 = zh, acc1 = zh, acc2 = zh, acc3 = zh;

  int nb = cnt >> 2;
  int4 ca = { 0, 0, 0, 0 }, cb = { 0, 0, 0, 0 };
  h2 nr10, nr11, nr12, nr13, nr20, nr21, nr22, nr23;
  h2 nr30, nr31, nr32, nr33, nr40, nr41, nr42, nr43;
  if (nb > 0) {
    const int4* p4 = (const int4*)p;
    ca = p4[0]; cb = p4[1];
    LOADM(nr1, ca.x); LOADM(nr2, ca.z); LOADM(nr3, cb.x); LOADM(nr4, cb.z);
  }
  for (int b = 0; b < nb; ++b) {
    int4 da = ca, db = cb;
    h2 m10 = nr10, m11 = nr11, m12 = nr12, m13 = nr13;
    h2 m20 = nr20, m21 = nr21, m22 = nr22, m23 = nr23;
    h2 m30 = nr30, m31 = nr31, m32 = nr32, m33 = nr33;
    h2 m40 = nr40, m41 = nr41, m42 = nr42, m43 = nr43;
    if (b + 1 < nb) {
      const int4* p4 = (const int4*)(p + (b + 1) * 4);
      ca = p4[0]; cb = p4[1];
      LOADM(nr1, ca.x); LOADM(nr2, ca.z); LOADM(nr3, cb.x); LOADM(nr4, cb.z);
    }
    float w1 = __int_as_float(da.y), w2 = __int_as_float(da.w);
    float w3 = __int_as_float(db.y), w4 = __int_as_float(db.w);
    wsum += (w1 + w2) + (w3 + w4);
    float p1 = edge_logit16(m10, m11, m12, m13, h2bcast(w1), hrd, we, at);
    float p2 = edge_logit16(m20, m21, m22, m23, h2bcast(w2), hrd, we, at);
    float p3 = edge_logit16(m30, m31, m32, m33, h2bcast(w3), hrd, we, at);
    float p4v = edge_logit16(m40, m41, m42, m43, h2bcast(w4), hrd, we, at);
    float mn = fmaxf(fmaxf(m, fmaxf(p1, p2)), fmaxf(p3, p4v));
    float sc = exp2f(m - mn);
    float t1 = exp2f(p1 - mn);
    float t2 = exp2f(p2 - mn);
    float t3 = exp2f(p3 - mn);
    float t4 = exp2f(p4v - mn);
    l = fmaf(l, sc, (t1 + t2) + (t3 + t4));
    h2 sch = h2bcast(sc);
    h2 t1h = h2bcast(t1), t2h = h2bcast(t2), t3h = h2bcast(t3), t4h = h2bcast(t4);
    acc0 = acc0 * sch + (t1h * m10 + (t2h * m20 + (t3h * m30 + t4h * m40)));
    acc1 = acc1 * sch + (t1h * m11 + (t2h * m21 + (t3h * m31 + t4h * m41)));
    acc2 = acc2 * sch + (t1h * m12 + (t2h * m22 + (t3h * m32 + t4h * m42)));
    acc3 = acc3 * sch + (t1h * m13 + (t2h * m23 + (t3h * m33 + t4h * m43)));
    m = mn;
  }
  for (int i = nb * 4; i < cnt; ++i) {
    int2 v1 = p[i];
    float w1 = __int_as_float(v1.y);
    h2 mm0, mm1, mm2, mm3;
    LOADM(mm, v1.x);
    wsum += w1;
    float p1 = edge_logit16(mm0, mm1, mm2, mm3, h2bcast(w1), hrd, we, at);
    float mn = fmaxf(m, p1);
    float sc = exp2f(m - mn);
    float t1 = exp2f(p1 - mn);
    l = fmaf(l, sc, t1);
    h2 sch = h2bcast(sc), t1h = h2bcast(t1);
    acc0 = acc0 * sch + t1h * mm0;
    acc1 = acc1 * sch + t1h * mm1;
    acc2 = acc2 * sch + t1h * mm2;
    acc3 = acc3 * sch + t1h * mm3;
    m = mn;
  }

  // ---- self-loop: edge_attr = mean of incoming ea ----
  float la = wsum / fmaxf((float)cnt, 1.f);
  h2 sl0, sl1, sl2, sl3;
  LOADM(sl, n);
  float ps = edge_logit16(sl0, sl1, sl2, sl3, h2bcast(la), hrd, we, at);
  float mn = fmaxf(m, ps);
  float sc = exp2f(m - mn);
  float ts = exp2f(ps - mn);
  l = fmaf(l, sc, ts);
  h2 sch = h2bcast(sc), tsh = h2bcast(ts);
  acc0 = acc0 * sch + tsh * sl0;
  acc1 = acc1 * sch + tsh * sl1;
  acc2 = acc2 * sch + tsh * sl2;
  acc3 = acc3 * sch + tsh * sl3;

  float inv = 1.f / l;
  float4 b0 = *(const float4*)(bias + j8);
  float4 b1 = *(const float4*)(bias + j8 + 4);
  h2 o0 = { (_Float16)fmaxf(fmaf((float)acc0.x, inv, b0.x), 0.f),
            (_Float16)fmaxf(fmaf((float)acc0.y, inv, b0.y), 0.f) };
  h2 o1 = { (_Float16)fmaxf(fmaf((float)acc1.x, inv, b0.z), 0.f),
            (_Float16)fmaxf(fmaf((float)acc1.y, inv, b0.w), 0.f) };
  h2 o2 = { (_Float16)fmaxf(fmaf((float)acc2.x, inv, b1.x), 0.f),
            (_Float16)fmaxf(fmaf((float)acc2.y, inv, b1.y), 0.f) };
  h2 o3 = { (_Float16)fmaxf(fmaf((float)acc3.x, inv, b1.z), 0.f),
            (_Float16)fmaxf(fmaf((float)acc3.y, inv, b1.w), 0.f) };
  int4 pk;
  pk.x = __builtin_bit_cast(int, o0);
  pk.y = __builtin_bit_cast(int, o1);
  pk.z = __builtin_bit_cast(int, o2);
  pk.w = __builtin_bit_cast(int, o3);
  *(int4*)(out + (size_t)n * 128 + j8) = pk;
}

// ---------- pool (batch is sorted, h fp16): 64 rows/block ----------
__global__ __launch_bounds__(128) void pool_kernel(
    const __half* __restrict__ h, const int* __restrict__ batch,
    float* __restrict__ pooled)
{
  int n0 = blockIdx.x * 64;
  if (n0 >= NN) return;
  int j = threadIdx.x;
  int nend = n0 + 64; if (nend > NN) nend = NN;
  float acc = 0.f;
  int curb = batch[n0];
  for (int n = n0; n < nend; ++n) {
    int b = batch[n];
    if (b != curb) {
      unsafeAtomicAdd(pooled + curb * 128 + j, acc);
      acc = 0.f; curb = b;
    }
    acc += __half2float(h[(size_t)n * 128 + j]);
  }
  unsafeAtomicAdd(pooled + curb * 128 + j, acc);
}

// ---------- fc ----------
__global__ __launch_bounds__(128) void fc_kernel(
    const float* __restrict__ pooled, const float* __restrict__ fcw,
    const float* __restrict__ fcb, float* __restrict__ out)
{
  int b = blockIdx.x;
  int t = threadIdx.x;
  float v = pooled[b * 128 + t] * fcw[t];
#pragma unroll
  for (int off = 32; off >= 1; off >>= 1) v += __shfl_down(v, off, 64);
  __shared__ float sbuf[2];
  if ((t & 63) == 0) sbuf[t >> 6] = v;
  __syncthreads();
  if (t == 0) out[b] = sbuf[0] + sbuf[1] + fcb[0];
}

extern "C" void kernel_launch(void* const* d_in, const int* in_sizes, int n_in,
                              void* d_out, int out_size, void* d_ws, size_t ws_size,
                              hipStream_t stream)
{
  const float* x    = (const float*)d_in[0];
  const int*   ei   = (const int*)d_in[1];
  const float* ea   = (const float*)d_in[2];
  const int*   batch= (const int*)d_in[3];
  const float* c1w  = (const float*)d_in[4];
  const float* c1b  = (const float*)d_in[5];
  const float* c2w  = (const float*)d_in[6];
  const float* c2b  = (const float*)d_in[7];
  const float* gWl[2] = { (const float*)d_in[8],  (const float*)d_in[13] };
  const float* gWr[2] = { (const float*)d_in[9],  (const float*)d_in[14] };
  const float* gWe[2] = { (const float*)d_in[10], (const float*)d_in[15] };
  const float* gAt[2] = { (const float*)d_in[11], (const float*)d_in[16] };
  const float* gB [2] = { (const float*)d_in[12], (const float*)d_in[17] };
  const float* fcw  = (const float*)d_in[18];
  const float* fcb  = (const float*)d_in[19];
  float* out = (float*)d_out;

  const int* src = ei;
  const int* dst = ei + EE;

  __half* h16    = (__half*)d_ws;                    // NN*128 fp16
  __half* hl     = h16 + (size_t)NN * 128;           // NN*128 fp16
  __half* hr     = hl + (size_t)NN * 128;            // NN*128 fp16
  int2*  pack    = (int2*)(hr + (size_t)NN * 128);   // NN*CAP int2
  int*   cursor  = (int*)(pack + (size_t)NN * CAP);  // NN i
  float* pooled  = (float*)(cursor + NN);            // BB*128 f
  unsigned int* Wp = (unsigned int*)(pooled + BB * 128); // 2 x 16384 u32 (WpT)
  int*   order   = (int*)(Wp + 32768);               // NN i
  int*   gcnt    = order + NN;                       // CAP+1 i
  int*   relbase = gcnt + (CAP + 1);                 // CAP+1 i

  wpack_kernel<<<NODE_B, 256, 0, stream>>>(gWl[0], gWr[0], gWl[1], gWr[1],
                                           Wp, cursor, gcnt, relbase, pooled);

  conv_scatter_kernel<<<CONVA_B, 256, 0, stream>>>(
      x, c1w, c1b, c2w, c2b, h16, src, dst, ea, cursor, pack);

  // gemm L0 carries scatter half B; cursor complete when it finishes
  gemm_dual<<<GEMMS_B, 256, 0, stream>>>(
      h16, Wp, hl, hr, src, dst, ea, cursor, pack, 1);

  // degree counting sort (2 dispatches: hist, place-with-local-prefix)
  hist_kernel<<<NODE_B, 256, 0, stream>>>(cursor, gcnt);
  place_kernel<<<NODE_B, 256, 0, stream>>>(cursor, gcnt, relbase, order);

  gat_node_kernel<<<(NN + 15) / 16, 256, 0, stream>>>(order, cursor, pack, hl, hr,
                                                      gWe[0], gAt[0], gB[0], h16);

  gemm_dual<<<GEMM_B, 256, 0, stream>>>(
      h16, Wp + 16384, hl, hr, src, dst, ea, cursor, pack, 0);
  gat_node_kernel<<<(NN + 15) / 16, 256, 0, stream>>>(order, cursor, pack, hl, hr,
                                                      gWe[1], gAt[1], gB[1], h16);

  pool_kernel<<<(NN + 63) / 64, 128, 0, stream>>>(h16, batch, pooled);
  fc_kernel<<<BB, 128, 0, stream>>>(pooled, fcw, fcb, out);
}